// Round 1
// baseline (505.888 us; speedup 1.0000x reference)
//
#include <hip/hip_runtime.h>
#include <hip/hip_bf16.h>

// AssignAttention: B=16, N=256, S=4096, C=512, H=8, hd=64
// out[b,n,h*64+c] = sum_s softmax_n(q.kT/8)[n,s]/max(rowsum,1) * key[b,s,h*64+c]
// d_out = [out, out_style] (identical copies), fp32.

typedef __attribute__((ext_vector_type(8))) short bf16x8;
typedef __attribute__((ext_vector_type(4))) float f32x4;

__device__ __forceinline__ unsigned short f2bf(float f) {
  union { __hip_bfloat16 h; unsigned short u; } cv;
  cv.h = __float2bfloat16(f);
  return cv.u;
}

// ---------------------------------------------------------------- prep: Wt[n][k] = bf16(W[k][n])
__global__ __launch_bounds__(256) void prep_w(const float* __restrict__ Wq,
                                              const float* __restrict__ Wk,
                                              unsigned short* __restrict__ WtQ,
                                              unsigned short* __restrict__ WtK) {
  int idx = blockIdx.x * 256 + threadIdx.x;   // 0 .. 262143
  int n = idx >> 9, k = idx & 511;
  WtQ[idx] = f2bf(Wq[k * 512 + n]);
  WtK[idx] = f2bf(Wk[k * 512 + n]);
}

// ---------------------------------------------------------------- GEMM: Y[m][n] = bf16( X[m][:] @ Wt[n][:] )
// X fp32 [M x 512] row-major, Wt bf16 [512 n x 512 k] (pre-transposed), Y bf16 [M x 512]
__global__ __launch_bounds__(256, 2) void gemm_xw(const float* __restrict__ X,
                                                  const unsigned short* __restrict__ Wt,
                                                  __hip_bfloat16* __restrict__ Y) {
  __shared__ unsigned short As[128][72];   // A[m][k], +8 pad -> 2-way max
  __shared__ unsigned short Bs[128][72];   // B[n][k]
  const int t = threadIdx.x;
  const int wave = t >> 6, lane = t & 63, l15 = lane & 15, quad = lane >> 4;
  const int m0 = blockIdx.x * 128, n0 = blockIdx.y * 128;
  const int wm = (wave >> 1) * 64, wn = (wave & 1) * 64;

  f32x4 acc[4][4];
#pragma unroll
  for (int i = 0; i < 4; ++i)
#pragma unroll
    for (int j = 0; j < 4; ++j) { f32x4 z = {0.f, 0.f, 0.f, 0.f}; acc[i][j] = z; }

  for (int k0 = 0; k0 < 512; k0 += 64) {
    __syncthreads();
#pragma unroll
    for (int i = 0; i < 8; ++i) {
      int lin = i * 256 + t;            // 0..2047
      int row = lin >> 4;               // 0..127
      int c4 = (lin & 15) << 2;         // 0,4,..,60
      float4 v = *reinterpret_cast<const float4*>(&X[(size_t)(m0 + row) * 512 + k0 + c4]);
      short4 s;
      s.x = (short)f2bf(v.x); s.y = (short)f2bf(v.y);
      s.z = (short)f2bf(v.z); s.w = (short)f2bf(v.w);
      *reinterpret_cast<short4*>(&As[row][c4]) = s;
      short4 wv = *reinterpret_cast<const short4*>(&Wt[(size_t)(n0 + row) * 512 + k0 + c4]);
      *reinterpret_cast<short4*>(&Bs[row][c4]) = wv;
    }
    __syncthreads();
#pragma unroll
    for (int x = 0; x < 2; ++x) {
      bf16x8 a[4], bfr[4];
#pragma unroll
      for (int i = 0; i < 4; ++i)
        a[i] = *reinterpret_cast<const bf16x8*>(&As[wm + 16 * i + l15][x * 32 + quad * 8]);
#pragma unroll
      for (int j = 0; j < 4; ++j)
        bfr[j] = *reinterpret_cast<const bf16x8*>(&Bs[wn + 16 * j + l15][x * 32 + quad * 8]);
#pragma unroll
      for (int i = 0; i < 4; ++i)
#pragma unroll
        for (int j = 0; j < 4; ++j)
          acc[i][j] = __builtin_amdgcn_mfma_f32_16x16x32_bf16(a[i], bfr[j], acc[i][j], 0, 0, 0);
    }
  }
  // epilogue: C/D layout col=lane&15, row=quad*4+reg
#pragma unroll
  for (int i = 0; i < 4; ++i)
#pragma unroll
    for (int j = 0; j < 4; ++j)
#pragma unroll
      for (int r = 0; r < 4; ++r) {
        int m = m0 + wm + 16 * i + 4 * quad + r;
        int n = n0 + wn + 16 * j + l15;
        Y[(size_t)m * 512 + n] = __float2bfloat16(acc[i][j][r]);
      }
}

// ---------------------------------------------------------------- fused attention
// grid 256: blk = bh*2 + chunk; per WG: q[256x64] (regs), loop 32 s-tiles of 64.
__global__ __launch_bounds__(256, 1) void attn_kernel(const __hip_bfloat16* __restrict__ qg,
                                                      const __hip_bfloat16* __restrict__ kg,
                                                      const float* __restrict__ keyg,
                                                      float* __restrict__ accg,
                                                      float* __restrict__ rsg) {
  __shared__ unsigned short ks[64][72];   // k_tile[s][c]
  __shared__ unsigned short vs[64][68];   // v_tile transposed [c][s], stride 68 -> 8B aligned rows
  __shared__ unsigned short ps[256][72];  // attn tile [n][s] (per-wave 64-row region)
  __shared__ float red[4][64];            // cross-wave column-sum partials

  const int t = threadIdx.x;
  const int wave = t >> 6, lane = t & 63, l15 = lane & 15, quad = lane >> 4;
  const int blk = blockIdx.x, chunk = blk & 1, bh = blk >> 1, b = bh >> 3, h = bh & 7;

  // q fragments in registers: rows [64*wave, +64), A-layout A[m=l15][k=quad*8+j]
  bf16x8 qf[4][2];
#pragma unroll
  for (int i = 0; i < 4; ++i)
#pragma unroll
    for (int x = 0; x < 2; ++x) {
      const unsigned short* p = (const unsigned short*)qg +
          (size_t)(b * 256 + wave * 64 + 16 * i + l15) * 512 + h * 64 + x * 32 + quad * 8;
      qf[i][x] = *reinterpret_cast<const bf16x8*>(p);
    }

  f32x4 oacc[4][4];
  float rs_[4][4];
#pragma unroll
  for (int i = 0; i < 4; ++i)
#pragma unroll
    for (int j = 0; j < 4; ++j) { f32x4 z = {0.f, 0.f, 0.f, 0.f}; oacc[i][j] = z; rs_[i][j] = 0.f; }

  const int s0base = chunk * 2048;
  for (int it = 0; it < 32; ++it) {
    const int s0 = s0base + it * 64;
    __syncthreads();  // protect ks/vs/red from previous iteration readers
    // stage k tile (bf16, rows of ks)
    {
      const unsigned short* kbase = (const unsigned short*)kg + ((size_t)(b * 4096 + s0)) * 512 + h * 64;
#pragma unroll
      for (int i = 0; i < 4; ++i) {
        int lin = i * 256 + t, row = lin >> 4, c4 = (lin & 15) << 2;
        *reinterpret_cast<short4*>(&ks[row][c4]) =
            *reinterpret_cast<const short4*>(kbase + (size_t)row * 512 + c4);
      }
      // stage v tile transposed, fp32 -> bf16
      const float* vbase = keyg + ((size_t)(b * 4096 + s0)) * 512 + h * 64;
#pragma unroll
      for (int i = 0; i < 4; ++i) {
        int lin = i * 256 + t, row = lin >> 4, c4 = (lin & 15) << 2;
        float4 v = *reinterpret_cast<const float4*>(vbase + (size_t)row * 512 + c4);
        vs[c4 + 0][row] = f2bf(v.x);
        vs[c4 + 1][row] = f2bf(v.y);
        vs[c4 + 2][row] = f2bf(v.z);
        vs[c4 + 3][row] = f2bf(v.w);
      }
    }
    __syncthreads();

    // L = q @ k_tile^T  (D rows = n-local, cols = s-local)
    f32x4 L[4][4];
#pragma unroll
    for (int i = 0; i < 4; ++i)
#pragma unroll
      for (int j = 0; j < 4; ++j) { f32x4 z = {0.f, 0.f, 0.f, 0.f}; L[i][j] = z; }
#pragma unroll
    for (int x = 0; x < 2; ++x) {
      bf16x8 bfr[4];
#pragma unroll
      for (int j = 0; j < 4; ++j)
        bfr[j] = *reinterpret_cast<const bf16x8*>(&ks[16 * j + l15][x * 32 + quad * 8]);
#pragma unroll
      for (int i = 0; i < 4; ++i)
#pragma unroll
        for (int j = 0; j < 4; ++j)
          L[i][j] = __builtin_amdgcn_mfma_f32_16x16x32_bf16(qf[i][x], bfr[j], L[i][j], 0, 0, 0);
    }

    // exp(l/8); column (n) sums: per-lane over i,r, then quads, then waves via LDS
    float csum[4] = {0.f, 0.f, 0.f, 0.f};
#pragma unroll
    for (int i = 0; i < 4; ++i)
#pragma unroll
      for (int j = 0; j < 4; ++j)
#pragma unroll
        for (int r = 0; r < 4; ++r) {
          float e = __expf(L[i][j][r] * 0.125f);
          L[i][j][r] = e;
          csum[j] += e;
        }
#pragma unroll
    for (int j = 0; j < 4; ++j) {
      float v = csum[j];
      v += __shfl_xor(v, 16);
      v += __shfl_xor(v, 32);
      csum[j] = v;
    }
    if (quad == 0) {
#pragma unroll
      for (int j = 0; j < 4; ++j) red[wave][16 * j + l15] = csum[j];
    }
    __syncthreads();
    float rcol[4];
#pragma unroll
    for (int j = 0; j < 4; ++j) {
      int s = 16 * j + l15;
      rcol[j] = 1.0f / (red[0][s] + red[1][s] + red[2][s] + red[3][s]);
    }

    // normalize -> attn; accumulate rowsum; write P tile (bf16) for A-operand reload
#pragma unroll
    for (int i = 0; i < 4; ++i)
#pragma unroll
      for (int r = 0; r < 4; ++r) {
        float rowpart = 0.f;
        int nloc = 16 * i + 4 * quad + r;
#pragma unroll
        for (int j = 0; j < 4; ++j) {
          float a = L[i][j][r] * rcol[j];
          rowpart += a;
          ps[wave * 64 + nloc][16 * j + l15] = f2bf(a);
        }
        rowpart += __shfl_xor(rowpart, 1);
        rowpart += __shfl_xor(rowpart, 2);
        rowpart += __shfl_xor(rowpart, 4);
        rowpart += __shfl_xor(rowpart, 8);
        rs_[i][r] += rowpart;
      }

    // O += P @ V   (B-operand from transposed vs)
#pragma unroll
    for (int x = 0; x < 2; ++x) {
      bf16x8 ap[4], bv[4];
#pragma unroll
      for (int i = 0; i < 4; ++i)
        ap[i] = *reinterpret_cast<const bf16x8*>(&ps[wave * 64 + 16 * i + l15][x * 32 + quad * 8]);
#pragma unroll
      for (int j = 0; j < 4; ++j) {
        const int* vp = reinterpret_cast<const int*>(&vs[16 * j + l15][x * 32 + quad * 8]);
        union { bf16x8 f; int w[4]; } u;
        u.w[0] = vp[0]; u.w[1] = vp[1]; u.w[2] = vp[2]; u.w[3] = vp[3];
        bv[j] = u.f;
      }
#pragma unroll
      for (int i = 0; i < 4; ++i)
#pragma unroll
        for (int j = 0; j < 4; ++j)
          oacc[i][j] = __builtin_amdgcn_mfma_f32_16x16x32_bf16(ap[i], bv[j], oacc[i][j], 0, 0, 0);
    }
  }

  // flush per-chunk partials (disjoint regions, no atomics)
  float* rsp = rsg + chunk * 32768 + bh * 256;
  if (l15 == 0) {
#pragma unroll
    for (int i = 0; i < 4; ++i)
#pragma unroll
      for (int r = 0; r < 4; ++r)
        rsp[wave * 64 + 16 * i + 4 * quad + r] = rs_[i][r];
  }
  float* ap_ = accg + (size_t)chunk * 2097152 + (size_t)bh * 16384;
#pragma unroll
  for (int i = 0; i < 4; ++i)
#pragma unroll
    for (int j = 0; j < 4; ++j)
#pragma unroll
      for (int r = 0; r < 4; ++r)
        ap_[(wave * 64 + 16 * i + 4 * quad + r) * 64 + 16 * j + l15] = oacc[i][j][r];
}

// ---------------------------------------------------------------- finalize: divide + write both outputs
__global__ __launch_bounds__(256) void finalize(const float* __restrict__ acc,
                                                const float* __restrict__ rs,
                                                float* __restrict__ out) {
  int idx = blockIdx.x * 256 + threadIdx.x;   // 0 .. 2097151
  int c = idx & 63, n = (idx >> 6) & 255, bh = idx >> 14;
  float v = acc[idx] + acc[idx + 2097152];
  float r = rs[bh * 256 + n] + rs[32768 + bh * 256 + n];
  float o = v / fmaxf(r, 1.0f);
  int b = bh >> 3, h = bh & 7;
  size_t oi = ((size_t)(b * 256 + n)) * 512 + h * 64 + c;
  out[oi] = o;
  out[oi + 2097152] = o;
}

extern "C" void kernel_launch(void* const* d_in, const int* in_sizes, int n_in,
                              void* d_out, int out_size, void* d_ws, size_t ws_size,
                              hipStream_t stream) {
  const float* query = (const float*)d_in[0];   // [16,256,512]
  const float* key   = (const float*)d_in[1];   // [16,4096,512]
  const float* Wq    = (const float*)d_in[2];   // [512,512]
  const float* Wk    = (const float*)d_in[3];   // [512,512]
  float* out = (float*)d_out;
  char* ws = (char*)d_ws;

  // ws layout (bytes):
  unsigned short* WtQ = (unsigned short*)(ws);                 // 512*512*2   = 524288
  unsigned short* WtK = (unsigned short*)(ws + 524288);        // 524288
  __hip_bfloat16* qbf = (__hip_bfloat16*)(ws + 1048576);       // 4096*512*2  = 4194304
  __hip_bfloat16* kbf = (__hip_bfloat16*)(ws + 5242880);       // 65536*512*2 = 67108864
  float* accw = (float*)(ws + 72351744);                       // 2*128*256*64*4 = 16777216
  float* rsw  = (float*)(ws + 89128960);                       // 2*128*256*4    = 262144
  // total: 89,391,104 bytes

  prep_w<<<1024, 256, 0, stream>>>(Wq, Wk, WtQ, WtK);
  gemm_xw<<<dim3(32, 4), 256, 0, stream>>>(query, WtQ, qbf);   // q = query @ Wq
  gemm_xw<<<dim3(512, 4), 256, 0, stream>>>(key, WtK, kbf);    // k = key @ Wk
  attn_kernel<<<256, 256, 0, stream>>>(qbf, kbf, key, accw, rsw);
  finalize<<<8192, 256, 0, stream>>>(accw, rsw, out);
}